// Round 2
// baseline (482.389 us; speedup 1.0000x reference)
//
#include <hip/hip_runtime.h>
#include <math.h>

// ForwardKinematics: B=524288, J=24, fp32. One thread per element, NO LDS.
// AoS layout is cache-friendly: per-thread float4 loads at 384B lane stride
// touch each 128B line 8x (7 L1 hits) -> no HBM over-fetch, no barriers,
// occupancy limited only by VGPRs.

#define NB 524288
#define NJ 24
#define BLOCK 256

namespace {
constexpr int PAR[NJ] = {-1,0,0,0,1,2,3,4,5,6,7,8,9,9,9,12,13,14,16,17,18,19,20,21};
}

__global__ __launch_bounds__(BLOCK)
void ForwardKinematics_51342039056994_kernel(
    const float* __restrict__ root_q,   // (B,4)
    const float* __restrict__ root_p,   // (B,3)
    const float* __restrict__ loc_q,    // (B,24,4)
    const float* __restrict__ bones,    // (B,24)
    const float* __restrict__ rest_d,   // (24,3)
    float* __restrict__ out)            // (B,24,3)
{
    const int b = blockIdx.x * BLOCK + threadIdx.x;

    const float4* lq   = (const float4*)loc_q + (size_t)b * NJ;     // 1 float4 per joint
    const float4* bsrc = (const float4*)bones + (size_t)b * (NJ/4); // 6 float4
    float4*       dst  = (float4*)out + (size_t)b * 18;             // 72 floats out

    float gqw[NJ], gqx[NJ], gqy[NJ], gqz[NJ];
    float gpx[NJ], gpy[NJ], gpz[NJ];

    // ---- bone lengths: 6 aligned float4 (issued early for mem parallelism) ----
    float bl[NJ];
    #pragma unroll
    for (int m = 0; m < NJ/4; ++m) {
        float4 v = bsrc[m];
        bl[4*m+0] = v.x; bl[4*m+1] = v.y; bl[4*m+2] = v.z; bl[4*m+3] = v.w;
    }

    // ---- root ----
    {
        float4 rq = ((const float4*)root_q)[b];
        float inv = 1.0f / (sqrtf(rq.x*rq.x + rq.y*rq.y + rq.z*rq.z + rq.w*rq.w) + 1e-8f);
        gqw[0] = rq.x * inv; gqx[0] = rq.y * inv; gqy[0] = rq.z * inv; gqz[0] = rq.w * inv;
        gpx[0] = root_p[b*3+0];
        gpy[0] = root_p[b*3+1];
        gpz[0] = root_p[b*3+2];
    }

    #pragma unroll
    for (int j = 1; j < NJ; ++j) {
        const int p = PAR[j];

        // local quat j: one aligned float4, lane stride 384B (L1-friendly)
        float4 l = lq[j];
        float lw = l.x, lx = l.y, ly = l.z, lz = l.w;
        float invn = 1.0f / (sqrtf(lw*lw + lx*lx + ly*ly + lz*lz) + 1e-8f);
        lw *= invn; lx *= invn; ly *= invn; lz *= invn;

        float pw = gqw[p], pqx = gqx[p], pqy = gqy[p], pqz = gqz[p];

        // glob_q[j] = parent_q * local_q  (dead for leaf joints -> DCE)
        gqw[j] = pw*lw - pqx*lx - pqy*ly - pqz*lz;
        gqx[j] = pw*lx + pqx*lw + pqy*lz - pqz*ly;
        gqy[j] = pw*ly - pqx*lz + pqy*lw + pqz*lx;
        gqz[j] = pw*lz + pqx*ly - pqy*lx + pqz*lw;

        // rotate rest_d[j] by parent quat (wave-uniform scalar loads)
        float dx = rest_d[3*j+0], dy = rest_d[3*j+1], dz = rest_d[3*j+2];
        float tx = 2.0f * (pqy*dz - pqz*dy);
        float ty = 2.0f * (pqz*dx - pqx*dz);
        float tz = 2.0f * (pqx*dy - pqy*dx);
        float rx = dx + pw*tx + (pqy*tz - pqz*ty);
        float ry = dy + pw*ty + (pqz*tx - pqx*tz);
        float rz = dz + pw*tz + (pqx*ty - pqy*tx);

        float L = bl[j];
        gpx[j] = gpx[p] + rx * L;
        gpy[j] = gpy[p] + ry * L;
        gpz[j] = gpz[p] + rz * L;

        // flush a completed 4-joint group as 3 aligned float4 stores
        // (lets leaf-position registers die early)
        if ((j & 3) == 3) {
            const int g = j >> 2;   // joints 4g..4g+3 -> float4 slots 3g..3g+2
            dst[3*g+0] = make_float4(gpx[j-3], gpy[j-3], gpz[j-3], gpx[j-2]);
            dst[3*g+1] = make_float4(gpy[j-2], gpz[j-2], gpx[j-1], gpy[j-1]);
            dst[3*g+2] = make_float4(gpz[j-1], gpx[j],   gpy[j],   gpz[j]);
        }
    }
}

extern "C" void kernel_launch(void* const* d_in, const int* in_sizes, int n_in,
                              void* d_out, int out_size, void* d_ws, size_t ws_size,
                              hipStream_t stream) {
    const float* root_q = (const float*)d_in[0];
    const float* root_p = (const float*)d_in[1];
    const float* loc_q  = (const float*)d_in[2];
    const float* bones  = (const float*)d_in[3];
    const float* rest_d = (const float*)d_in[4];
    float* out = (float*)d_out;

    dim3 grid(NB / BLOCK);
    dim3 block(BLOCK);
    ForwardKinematics_51342039056994_kernel<<<grid, block, 0, stream>>>(
        root_q, root_p, loc_q, bones, rest_d, out);
}

// Round 3
// 449.962 us; speedup vs baseline: 1.0721x; 1.0721x over previous
//
#include <hip/hip_runtime.h>
#include <math.h>

// ForwardKinematics: B=524288, J=24, fp32.
// Chunked pipeline: joints in 6 groups of 4. Per group: coalesced global->reg
// prefetch (issued one group ahead), reg->LDS transposed scatter, per-thread
// compute from LDS columns, transposed pos buffer, cooperative float4 stores.
// LDS = 28 rows x 132 cols x 4B = 14.8 KB -> ~11 blocks/CU.
// Col stride 132: all LDS access <=2-way bank aliasing (free on gfx950).

#define NB 524288
#define NJ 24
#define BLOCK 128
#define SL 132
#define QROWS 16
#define PROWS 12

namespace {
constexpr int PAR[NJ] = {-1,0,0,0,1,2,3,4,5,6,7,8,9,9,9,12,13,14,16,17,18,19,20,21};
}

__global__ __launch_bounds__(BLOCK, 5)
void ForwardKinematics_51342039056994_kernel(
    const float* __restrict__ root_q,   // (B,4)
    const float* __restrict__ root_p,   // (B,3)
    const float* __restrict__ loc_q,    // (B,24,4)
    const float* __restrict__ bones,    // (B,24)
    const float* __restrict__ rest_d,   // (24,3)
    float* __restrict__ out)            // (B,24,3)
{
    __shared__ float qbuf[QROWS * SL];  // group's local quats, rows 4*jj+c, col=elem
    __shared__ float pbuf[PROWS * SL];  // group's positions, rows jj*3+c, col=elem

    const int tid  = threadIdx.x;
    const int base = blockIdx.x * BLOCK;
    const int b    = base + tid;

    const float4* lq4 = (const float4*)loc_q;   // idx: elem*24 + j
    const float4* bn4 = (const float4*)bones;   // idx: elem*6 + g
    float4*       o4  = (float4*)out;           // idx: elem*18 + g*3 + r

    // staging map: thread stages quat of joint (4g + sw) for element (m*32 + tid/4)
    const int sa = tid >> 2;   // 0..31
    const int sw = tid & 3;    // 0..3

    // ---- prologue: prefetch group 0 quats, group 0 bones, root ----
    float4 q_pre[4];
    #pragma unroll
    for (int m = 0; m < 4; ++m)
        q_pre[m] = lq4[(m*32 + sa + base) * NJ + sw];
    float4 bl4 = bn4[b * 6 + 0];
    float4 rq  = ((const float4*)root_q)[b];
    float rpx = root_p[b*3+0], rpy = root_p[b*3+1], rpz = root_p[b*3+2];

    float gqw[NJ], gqx[NJ], gqy[NJ], gqz[NJ];
    float gpx[NJ], gpy[NJ], gpz[NJ];
    {
        float inv = 1.0f / (sqrtf(rq.x*rq.x + rq.y*rq.y + rq.z*rq.z + rq.w*rq.w) + 1e-8f);
        gqw[0] = rq.x*inv; gqx[0] = rq.y*inv; gqy[0] = rq.z*inv; gqz[0] = rq.w*inv;
        gpx[0] = rpx; gpy[0] = rpy; gpz[0] = rpz;
    }

    #pragma unroll
    for (int g = 0; g < 6; ++g) {
        // ---- scatter staged quats into transposed LDS ----
        #pragma unroll
        for (int m = 0; m < 4; ++m) {
            const int elem = m*32 + sa;
            float4 v = q_pre[m];
            qbuf[(4*sw + 0)*SL + elem] = v.x;
            qbuf[(4*sw + 1)*SL + elem] = v.y;
            qbuf[(4*sw + 2)*SL + elem] = v.z;
            qbuf[(4*sw + 3)*SL + elem] = v.w;
        }
        // ---- prefetch next group (latency hidden behind compute+store) ----
        float4 bl4_n = bl4;
        if (g < 5) {
            #pragma unroll
            for (int m = 0; m < 4; ++m)
                q_pre[m] = lq4[(m*32 + sa + base) * NJ + (g+1)*4 + sw];
            bl4_n = bn4[b * 6 + (g+1)];
        }
        __syncthreads();   // qbuf ready; pbuf(g-1) reads complete

        // ---- compute joints 4g .. 4g+3 ----
        const float blv[4] = { bl4.x, bl4.y, bl4.z, bl4.w };
        #pragma unroll
        for (int jj = 0; jj < 4; ++jj) {
            const int j = 4*g + jj;
            if (j == 0) {
                pbuf[0*SL + tid] = gpx[0];
                pbuf[1*SL + tid] = gpy[0];
                pbuf[2*SL + tid] = gpz[0];
                continue;
            }
            const int p = PAR[j];
            float lw = qbuf[(4*jj + 0)*SL + tid];
            float lx = qbuf[(4*jj + 1)*SL + tid];
            float ly = qbuf[(4*jj + 2)*SL + tid];
            float lz = qbuf[(4*jj + 3)*SL + tid];
            float invn = 1.0f / (sqrtf(lw*lw + lx*lx + ly*ly + lz*lz) + 1e-8f);
            lw *= invn; lx *= invn; ly *= invn; lz *= invn;

            const float pw = gqw[p], pqx = gqx[p], pqy = gqy[p], pqz = gqz[p];

            // glob_q[j] = parent_q * local_q (leaves DCE'd)
            gqw[j] = pw*lw - pqx*lx - pqy*ly - pqz*lz;
            gqx[j] = pw*lx + pqx*lw + pqy*lz - pqz*ly;
            gqy[j] = pw*ly - pqx*lz + pqy*lw + pqz*lx;
            gqz[j] = pw*lz + pqx*ly - pqy*lx + pqz*lw;

            // rotate rest_d[j] by parent quat (uniform-address scalar loads)
            const float dx = rest_d[3*j+0], dy = rest_d[3*j+1], dz = rest_d[3*j+2];
            float tx = 2.0f * (pqy*dz - pqz*dy);
            float ty = 2.0f * (pqz*dx - pqx*dz);
            float tz = 2.0f * (pqx*dy - pqy*dx);
            float rx = dx + pw*tx + (pqy*tz - pqz*ty);
            float ry = dy + pw*ty + (pqz*tx - pqx*tz);
            float rz = dz + pw*tz + (pqx*ty - pqy*tx);

            const float L = blv[jj];
            gpx[j] = gpx[p] + rx*L;
            gpy[j] = gpy[p] + ry*L;
            gpz[j] = gpz[p] + rz*L;

            pbuf[(jj*3 + 0)*SL + tid] = gpx[j];
            pbuf[(jj*3 + 1)*SL + tid] = gpy[j];
            pbuf[(jj*3 + 2)*SL + tid] = gpz[j];
        }
        __syncthreads();   // pbuf ready; qbuf consumed

        // ---- cooperative coalesced store: 128 elems * 3 float4 ----
        #pragma unroll
        for (int m = 0; m < 3; ++m) {
            const int f = m*BLOCK + tid;
            const int elem = f / 3;          // magic-mul
            const int r = f - elem*3;        // which float4 of the 12-float chunk
            float4 v;
            v.x = pbuf[(r*4 + 0)*SL + elem];
            v.y = pbuf[(r*4 + 1)*SL + elem];
            v.z = pbuf[(r*4 + 2)*SL + elem];
            v.w = pbuf[(r*4 + 3)*SL + elem];
            o4[(base + elem)*18 + g*3 + r] = v;
        }
        bl4 = bl4_n;
    }
}

extern "C" void kernel_launch(void* const* d_in, const int* in_sizes, int n_in,
                              void* d_out, int out_size, void* d_ws, size_t ws_size,
                              hipStream_t stream) {
    const float* root_q = (const float*)d_in[0];
    const float* root_p = (const float*)d_in[1];
    const float* loc_q  = (const float*)d_in[2];
    const float* bones  = (const float*)d_in[3];
    const float* rest_d = (const float*)d_in[4];
    float* out = (float*)d_out;

    dim3 grid(NB / BLOCK);
    dim3 block(BLOCK);
    ForwardKinematics_51342039056994_kernel<<<grid, block, 0, stream>>>(
        root_q, root_p, loc_q, bones, rest_d, out);
}